// Round 1
// baseline (66.928 us; speedup 1.0000x reference)
//
#include <hip/hip_runtime.h>
#include <cstddef>

// VectorizedPatchfier: capacity-limited stable counting sort into per-patch buffers.
// B=8, S=1<<20, C=4, grid 4x4 patches of 128x128 over a 512x512 canvas.

#define GRID_W 4
#define GRID_H 4
#define NPATCH 16
#define PATCH_SHIFT 7   // 128
#define S_LEN (1 << 20)

__device__ __forceinline__ int patch_of(float fx, float fy) {
    int px = ((int)fx) >> PATCH_SHIFT;
    int py = ((int)fy) >> PATCH_SHIFT;
    px = px < 0 ? 0 : (px > GRID_W - 1 ? GRID_W - 1 : px);
    py = py < 0 ? 0 : (py > GRID_H - 1 ? GRID_H - 1 : py);
    return (py << 2) | px;
}

// Per-wave: mask of lanes whose 4-bit patch id matches this lane's.
__device__ __forceinline__ unsigned long long same_mask4(int p) {
    unsigned long long same = ~0ull;
#pragma unroll
    for (int b = 0; b < 4; ++b) {
        unsigned long long bal = __ballot((p >> b) & 1);
        same &= ((p >> b) & 1) ? bal : ~bal;
    }
    return same;
}

// K1: per-tile 16-bin histogram. counts[t][p]
__global__ void k_hist(const float2* __restrict__ ev2, unsigned* __restrict__ counts,
                       int tile) {
    const int t = blockIdx.x;
    const int tid = threadIdx.x;
    __shared__ unsigned hist[NPATCH];
    if (tid < NPATCH) hist[tid] = 0;
    __syncthreads();
    const size_t base = (size_t)t * tile;
    const int iters = tile >> 8;  // tile / 256
    const int lane = tid & 63;
    const unsigned long long lt = (1ull << lane) - 1ull;
    for (int it = 0; it < iters; ++it) {
        size_t i = base + (size_t)it * 256 + tid;
        float2 xy = ev2[i * 2];  // x,y of event i (stride-16B dwordx2)
        int p = patch_of(xy.x, xy.y);
        unsigned long long same = same_mask4(p);
        if ((same & lt) == 0ull)  // leader lane of this group in this wave
            atomicAdd(&hist[p], (unsigned)__popcll(same));
    }
    __syncthreads();
    if (tid < NPATCH) counts[(size_t)t * NPATCH + tid] = hist[tid];
}

// K2: exclusive prefix per (batch, patch) over that batch's tiles, in place.
__global__ void k_scan(unsigned* __restrict__ counts, int tpb) {
    const int b = blockIdx.x >> 4;
    const int p = blockIdx.x & 15;
    const int tid = threadIdx.x;
    __shared__ unsigned buf[512];
    unsigned carry = 0;
    for (int c = 0; c < tpb; c += 512) {
        int t = c + tid;
        unsigned v = (t < tpb) ? counts[((size_t)(b * tpb + t)) * NPATCH + p] : 0u;
        buf[tid] = v;
        __syncthreads();
        for (int d = 1; d < 512; d <<= 1) {
            unsigned x = (tid >= d) ? buf[tid - d] : 0u;
            __syncthreads();
            buf[tid] += x;
            __syncthreads();
        }
        unsigned incl = buf[tid];
        unsigned total = buf[511];
        if (t < tpb) counts[((size_t)(b * tpb + t)) * NPATCH + p] = carry + incl - v;
        carry += total;
        __syncthreads();
    }
}

// K3: one wave per tile; stable rank = scanned offset + LDS running count + intra-wave rank.
__global__ void k_scatter(const float4* __restrict__ ev, const unsigned* __restrict__ offs,
                          const int* __restrict__ p_cap, float* __restrict__ out,
                          int tile, int tpb, int B) {
    const int t = blockIdx.x;
    const int lane = threadIdx.x;
    const unsigned cap = (unsigned)p_cap[0];
    const int b = t / tpb;

    __shared__ unsigned cnt[NPATCH];
    unsigned off0 = 0xFFFFFFFFu;
    if (lane < NPATCH) {
        off0 = offs[(size_t)t * NPATCH + lane];
        cnt[lane] = off0;
    }
    // prune: every group of this tile's batch already at capacity -> nothing to write
    if (!__any(lane < NPATCH && off0 < cap)) return;
    __syncthreads();

    float* __restrict__ out_mask = out + (size_t)B * NPATCH * cap * 4;
    const size_t base = (size_t)t * tile;
    const int iters = tile >> 6;  // tile / 64
    const unsigned long long lt = (1ull << lane) - 1ull;

    for (int it = 0; it < iters; ++it) {
        size_t i = base + (size_t)it * 64 + lane;
        float4 e = ev[i];
        int ix = (int)e.x, iy = (int)e.y;
        int px = ix >> PATCH_SHIFT;
        px = px < 0 ? 0 : (px > GRID_W - 1 ? GRID_W - 1 : px);
        int py = iy >> PATCH_SHIFT;
        py = py < 0 ? 0 : (py > GRID_H - 1 ? GRID_H - 1 : py);
        int p = (py << 2) | px;

        unsigned long long same = same_mask4(p);
        unsigned before = (unsigned)__popcll(same & lt);
        unsigned cbase = cnt[p];
        unsigned rank = cbase + before;
        if (rank < cap) {
            size_t g = (size_t)b * NPATCH + p;
            size_t o = g * cap + rank;
            float4 w;
            w.x = e.x - (float)(px << PATCH_SHIFT);
            w.y = e.y - (float)(py << PATCH_SHIFT);
            w.z = e.z;
            w.w = e.w;
            ((float4*)out)[o] = w;
            out_mask[o] = 1.0f;
        }
        if (before == 0) cnt[p] = cbase + (unsigned)__popcll(same);
        __syncthreads();  // order LDS cnt updates across iterations (single wave)
    }
}

extern "C" void kernel_launch(void* const* d_in, const int* in_sizes, int n_in,
                              void* d_out, int out_size, void* d_ws, size_t ws_size,
                              hipStream_t stream) {
    const float* events = (const float*)d_in[0];
    const int* p_cap = (const int*)d_in[1];

    const int C = 4;
    const long long N = (long long)in_sizes[0] / C;  // B*S
    const int B = (int)(N / S_LEN);

    int tile = 2048;
    while ((size_t)(N / tile) * NPATCH * sizeof(unsigned) > ws_size && tile < S_LEN)
        tile <<= 1;
    const int T = (int)(N / tile);
    const int tpb = S_LEN / tile;

    unsigned* counts = (unsigned*)d_ws;

    hipMemsetAsync(d_out, 0, (size_t)out_size * sizeof(float), stream);
    k_hist<<<T, 256, 0, stream>>>((const float2*)events, counts, tile);
    k_scan<<<B * NPATCH, 512, 0, stream>>>(counts, tpb);
    k_scatter<<<T, 64, 0, stream>>>((const float4*)events, counts, p_cap, (float*)d_out,
                                    tile, tpb, B);
}

// Round 2
// 52.856 us; speedup vs baseline: 1.2662x; 1.2662x over previous
//
#include <hip/hip_runtime.h>
#include <cstddef>

// VectorizedPatchfier: capacity-limited stable counting sort into per-patch buffers.
// B=8, S=1<<20, C=4, grid 4x4 patches of 128x128 over a 512x512 canvas.

#define GRID_W 4
#define GRID_H 4
#define NPATCH 16
#define PATCH_SHIFT 7   // 128
#define S_LEN (1 << 20)

__device__ __forceinline__ int patch_of(float fx, float fy) {
    int px = ((int)fx) >> PATCH_SHIFT;
    int py = ((int)fy) >> PATCH_SHIFT;
    px = px < 0 ? 0 : (px > GRID_W - 1 ? GRID_W - 1 : px);
    py = py < 0 ? 0 : (py > GRID_H - 1 ? GRID_H - 1 : py);
    return (py << 2) | px;
}

// Per-wave: mask of lanes whose 4-bit patch id matches this lane's.
__device__ __forceinline__ unsigned long long same_mask4(int p) {
    unsigned long long same = ~0ull;
#pragma unroll
    for (int b = 0; b < 4; ++b) {
        unsigned long long bal = __ballot((p >> b) & 1);
        same &= ((p >> b) & 1) ? bal : ~bal;
    }
    return same;
}

// K1: per-tile 16-bin histogram. counts[t][p]
__global__ void k_hist(const float2* __restrict__ ev2, unsigned* __restrict__ counts,
                       int tile) {
    const int t = blockIdx.x;
    const int tid = threadIdx.x;
    __shared__ unsigned hist[NPATCH];
    if (tid < NPATCH) hist[tid] = 0;
    __syncthreads();
    const size_t base = (size_t)t * tile;
    const int iters = tile >> 8;  // tile / 256
    const int lane = tid & 63;
    const unsigned long long lt = (1ull << lane) - 1ull;
    for (int it = 0; it < iters; ++it) {
        size_t i = base + (size_t)it * 256 + tid;
        float2 xy = ev2[i * 2];  // x,y of event i (stride-16B dwordx2)
        int p = patch_of(xy.x, xy.y);
        unsigned long long same = same_mask4(p);
        if ((same & lt) == 0ull)  // leader lane of this group in this wave
            atomicAdd(&hist[p], (unsigned)__popcll(same));
    }
    __syncthreads();
    if (tid < NPATCH) counts[(size_t)t * NPATCH + tid] = hist[tid];
}

// K2: exclusive prefix per (batch, patch) over that batch's tiles, in place.
// Also writes per-group totals to totals[b*16+p].
__global__ void k_scan(unsigned* __restrict__ counts, unsigned* __restrict__ totals,
                       int tpb) {
    const int b = blockIdx.x >> 4;
    const int p = blockIdx.x & 15;
    const int tid = threadIdx.x;
    __shared__ unsigned buf[512];
    unsigned carry = 0;
    for (int c = 0; c < tpb; c += 512) {
        int t = c + tid;
        unsigned v = (t < tpb) ? counts[((size_t)(b * tpb + t)) * NPATCH + p] : 0u;
        buf[tid] = v;
        __syncthreads();
        for (int d = 1; d < 512; d <<= 1) {
            unsigned x = (tid >= d) ? buf[tid - d] : 0u;
            __syncthreads();
            buf[tid] += x;
            __syncthreads();
        }
        unsigned incl = buf[tid];
        unsigned total = buf[511];
        if (t < tpb) counts[((size_t)(b * tpb + t)) * NPATCH + p] = carry + incl - v;
        carry += total;
        __syncthreads();
    }
    if (tid == 0) totals[blockIdx.x] = carry;
}

// K_tail: zero only the unfilled tail [min(total,cap), cap) of each group.
__global__ void k_tail(const unsigned* __restrict__ totals, const int* __restrict__ p_cap,
                       float* __restrict__ out, int B) {
    const unsigned cap = (unsigned)p_cap[0];
    const int g = blockIdx.x;
    const unsigned total = totals[g];
    const unsigned start = total < cap ? total : cap;
    if (start >= cap) return;
    float* __restrict__ out_mask = out + (size_t)B * NPATCH * cap * 4;
    float4 z = make_float4(0.f, 0.f, 0.f, 0.f);
    for (unsigned idx = start + threadIdx.x; idx < cap; idx += blockDim.x) {
        size_t o = (size_t)g * cap + idx;
        ((float4*)out)[o] = z;
        out_mask[o] = 0.0f;
    }
}

// K3: 4 waves per tile; each wave owns a contiguous 512-event chunk.
// Pass1: per-wave histogram (LDS, leader-lane updates). Pass2: scatter with
// per-wave private counters — stable: tile -> wave chunk -> iter -> lane order.
__global__ void k_scatter(const float4* __restrict__ ev, const unsigned* __restrict__ offs,
                          const int* __restrict__ p_cap, float* __restrict__ out,
                          int tile, int tpb, int B) {
    const int t = blockIdx.x;
    const int tid = threadIdx.x;
    const int lane = tid & 63;
    const int w = tid >> 6;  // 0..3
    const unsigned cap = (unsigned)p_cap[0];
    const int b = t / tpb;

    __shared__ unsigned base_off[NPATCH];
    __shared__ unsigned whist[4][NPATCH];
    __shared__ unsigned cnt[4][NPATCH];
    __shared__ int anyact;

    if (tid == 0) anyact = 0;
    __syncthreads();
    if (tid < NPATCH) {
        unsigned v = offs[(size_t)t * NPATCH + tid];
        base_off[tid] = v;
        if (v < cap) anyact = 1;  // benign race (flag set)
    }
    if (tid < 64) whist[tid >> 4][tid & 15] = 0;
    __syncthreads();
    if (!anyact) return;  // whole tile beyond capacity for every patch

    const float2* __restrict__ ev2 = (const float2*)ev;
    const int chunk = tile >> 2;          // events per wave
    const int iters = chunk >> 6;         // 64 events per iter
    const size_t cbase = (size_t)t * tile + (size_t)w * chunk;
    const unsigned long long lt = (1ull << lane) - 1ull;

    // Pass 1: per-wave histogram of its chunk.
    for (int it = 0; it < iters; ++it) {
        size_t i = cbase + (size_t)it * 64 + lane;
        float2 xy = ev2[i * 2];
        int p = patch_of(xy.x, xy.y);
        unsigned long long same = same_mask4(p);
        if ((same & lt) == 0ull)  // leader: private per-wave slot, no atomic
            whist[w][p] += (unsigned)__popcll(same);
    }
    __syncthreads();

    // Per-wave, per-patch start offsets.
    if (tid < 64) {
        int ww = tid >> 4, p = tid & 15;
        unsigned s = base_off[p];
        for (int w2 = 0; w2 < ww; ++w2) s += whist[w2][p];
        cnt[ww][p] = s;
    }
    __syncthreads();

    // Pass 2: scatter (chunk is L1-hot from pass 1). No barriers needed:
    // per-wave counters, intra-wave LDS ordering is program order.
    float* __restrict__ out_mask = out + (size_t)B * NPATCH * cap * 4;
    for (int it = 0; it < iters; ++it) {
        size_t i = cbase + (size_t)it * 64 + lane;
        float4 e = ev[i];
        int px = ((int)e.x) >> PATCH_SHIFT;
        px = px < 0 ? 0 : (px > GRID_W - 1 ? GRID_W - 1 : px);
        int py = ((int)e.y) >> PATCH_SHIFT;
        py = py < 0 ? 0 : (py > GRID_H - 1 ? GRID_H - 1 : py);
        int p = (py << 2) | px;

        unsigned long long same = same_mask4(p);
        unsigned before = (unsigned)__popcll(same & lt);
        unsigned cb = cnt[w][p];
        unsigned rank = cb + before;
        if (rank < cap) {
            size_t o = ((size_t)b * NPATCH + p) * cap + rank;
            float4 v;
            v.x = e.x - (float)(px << PATCH_SHIFT);
            v.y = e.y - (float)(py << PATCH_SHIFT);
            v.z = e.z;
            v.w = e.w;
            ((float4*)out)[o] = v;
            out_mask[o] = 1.0f;
        }
        if (before == 0) cnt[w][p] = cb + (unsigned)__popcll(same);
    }
}

extern "C" void kernel_launch(void* const* d_in, const int* in_sizes, int n_in,
                              void* d_out, int out_size, void* d_ws, size_t ws_size,
                              hipStream_t stream) {
    const float* events = (const float*)d_in[0];
    const int* p_cap = (const int*)d_in[1];

    const int C = 4;
    const long long N = (long long)in_sizes[0] / C;  // B*S
    const int B = (int)(N / S_LEN);

    int tile = 2048;
    while ((size_t)((N / tile) * NPATCH + B * NPATCH) * sizeof(unsigned) > ws_size &&
           tile < S_LEN)
        tile <<= 1;
    const int T = (int)(N / tile);
    const int tpb = S_LEN / tile;

    unsigned* counts = (unsigned*)d_ws;
    unsigned* totals = counts + (size_t)T * NPATCH;

    k_hist<<<T, 256, 0, stream>>>((const float2*)events, counts, tile);
    k_scan<<<B * NPATCH, 512, 0, stream>>>(counts, totals, tpb);
    k_tail<<<B * NPATCH, 256, 0, stream>>>(totals, p_cap, (float*)d_out, B);
    k_scatter<<<T, 256, 0, stream>>>((const float4*)events, counts, p_cap, (float*)d_out,
                                     tile, tpb, B);
}

// Round 3
// 37.947 us; speedup vs baseline: 1.7637x; 1.3929x over previous
//
#include <hip/hip_runtime.h>
#include <cstddef>

// VectorizedPatchfier: capacity-limited stable counting sort into per-patch buffers.
// B=8, S=1<<20, C=4, grid 4x4 patches of 128x128 over a 512x512 canvas.
// Two-phase count: only the first quarter of each batch is histogrammed; if every
// group saturates (total >= cap) within it -- true for uniform inputs with huge
// margin -- the fallback kernels early-exit and the suffix is never read.

#define GRID_W 4
#define GRID_H 4
#define NPATCH 16
#define PATCH_SHIFT 7   // 128
#define S_LEN (1 << 20)

__device__ __forceinline__ int patch_of(float fx, float fy) {
    int px = ((int)fx) >> PATCH_SHIFT;
    int py = ((int)fy) >> PATCH_SHIFT;
    px = px < 0 ? 0 : (px > GRID_W - 1 ? GRID_W - 1 : px);
    py = py < 0 ? 0 : (py > GRID_H - 1 ? GRID_H - 1 : py);
    return (py << 2) | px;
}

// Per-wave: mask of lanes whose 4-bit patch id matches this lane's.
__device__ __forceinline__ unsigned long long same_mask4(int p) {
    unsigned long long same = ~0ull;
#pragma unroll
    for (int b = 0; b < 4; ++b) {
        unsigned long long bal = __ballot((p >> b) & 1);
        same &= ((p >> b) & 1) ? bal : ~bal;
    }
    return same;
}

// K1a: histogram of phase-1 tiles (first T1pb per batch); stores per-wave hists.
__global__ void k_hist1(const float4* __restrict__ ev, unsigned* __restrict__ counts,
                        unsigned* __restrict__ whist_g, int tile, int tpb, int T1pb) {
    const int blk = blockIdx.x;
    const int b = blk / T1pb, tloc = blk - b * T1pb;
    const int t = b * tpb + tloc;
    const int tid = threadIdx.x, lane = tid & 63, w = tid >> 6;
    __shared__ unsigned wh[4][NPATCH];
    if (tid < 64) wh[tid >> 4][tid & 15] = 0;
    __syncthreads();
    const int chunk = tile >> 2, iters = chunk >> 6;
    const size_t cbase = (size_t)t * tile + (size_t)w * chunk;
    const unsigned long long lt = (1ull << lane) - 1ull;
    for (int it = 0; it < iters; ++it) {
        float4 e = ev[cbase + (size_t)it * 64 + lane];
        int p = patch_of(e.x, e.y);
        unsigned long long same = same_mask4(p);
        if ((same & lt) == 0ull) wh[w][p] += (unsigned)__popcll(same);
    }
    __syncthreads();
    if (tid < 64) whist_g[(size_t)blk * 64 + tid] = wh[tid >> 4][tid & 15];
    if (tid < NPATCH)
        counts[(size_t)t * NPATCH + tid] =
            wh[0][tid] + wh[1][tid] + wh[2][tid] + wh[3][tid];
}

// K1b (fallback): histogram of suffix tiles; early-exits when batch saturated.
__global__ void k_hist2(const float4* __restrict__ ev, unsigned* __restrict__ counts,
                        const unsigned* __restrict__ totals1, const int* __restrict__ p_cap,
                        int tile, int tpb, int T1pb) {
    const int nsuf = tpb - T1pb;
    const int b = blockIdx.x / nsuf;
    const int tloc = T1pb + (blockIdx.x - b * nsuf);
    const int t = b * tpb + tloc;
    const int tid = threadIdx.x, lane = tid & 63, w = tid >> 6;
    const unsigned cap = (unsigned)p_cap[0];
    __shared__ int s_sat;
    __shared__ unsigned wh[4][NPATCH];
    if (tid == 0) s_sat = 1;
    __syncthreads();
    if (tid < 16 && totals1[b * 16 + tid] < cap) s_sat = 0;  // benign race
    if (tid < 64) wh[tid >> 4][tid & 15] = 0;
    __syncthreads();
    if (s_sat) return;
    const int chunk = tile >> 2, iters = chunk >> 6;
    const size_t cbase = (size_t)t * tile + (size_t)w * chunk;
    const unsigned long long lt = (1ull << lane) - 1ull;
    for (int it = 0; it < iters; ++it) {
        float4 e = ev[cbase + (size_t)it * 64 + lane];
        int p = patch_of(e.x, e.y);
        unsigned long long same = same_mask4(p);
        if ((same & lt) == 0ull) wh[w][p] += (unsigned)__popcll(same);
    }
    __syncthreads();
    if (tid < NPATCH)
        counts[(size_t)t * NPATCH + tid] =
            wh[0][tid] + wh[1][tid] + wh[2][tid] + wh[3][tid];
}

// K2a: exclusive prefix over phase-1 tiles per (batch,patch); totals1 = prefix sum.
__global__ void k_scan1(unsigned* __restrict__ counts, unsigned* __restrict__ totals1,
                        int tpb, int T1pb) {
    const int b = blockIdx.x >> 4, p = blockIdx.x & 15;
    const int tid = threadIdx.x;
    __shared__ unsigned buf[512];
    unsigned carry = 0;
    for (int c = 0; c < T1pb; c += 512) {
        int tloc = c + tid;
        unsigned v = (tloc < T1pb) ? counts[((size_t)(b * tpb + tloc)) * NPATCH + p] : 0u;
        buf[tid] = v;
        __syncthreads();
        for (int d = 1; d < 512; d <<= 1) {
            unsigned x = (tid >= d) ? buf[tid - d] : 0u;
            __syncthreads();
            buf[tid] += x;
            __syncthreads();
        }
        if (tloc < T1pb) counts[((size_t)(b * tpb + tloc)) * NPATCH + p] = carry + buf[tid] - v;
        carry += buf[511];
        __syncthreads();
    }
    if (tid == 0) totals1[blockIdx.x] = carry;
}

// K2b (fallback): continue scan over suffix + zero unfilled tails. Early-exits
// when batch saturated (no tail exists then).
__global__ void k_scan2(unsigned* __restrict__ counts, const unsigned* __restrict__ totals1,
                        const int* __restrict__ p_cap, float* __restrict__ out,
                        int tpb, int T1pb, int B) {
    const unsigned cap = (unsigned)p_cap[0];
    const int b = blockIdx.x >> 4, p = blockIdx.x & 15;
    const int tid = threadIdx.x;
    __shared__ int s_sat;
    __shared__ unsigned buf[512];
    if (tid == 0) s_sat = 1;
    __syncthreads();
    if (tid < 16 && totals1[b * 16 + tid] < cap) s_sat = 0;  // benign race
    __syncthreads();
    if (s_sat) return;
    unsigned carry = totals1[blockIdx.x];
    for (int c = T1pb; c < tpb; c += 512) {
        int tloc = c + tid;
        unsigned v = (tloc < tpb) ? counts[((size_t)(b * tpb + tloc)) * NPATCH + p] : 0u;
        buf[tid] = v;
        __syncthreads();
        for (int d = 1; d < 512; d <<= 1) {
            unsigned x = (tid >= d) ? buf[tid - d] : 0u;
            __syncthreads();
            buf[tid] += x;
            __syncthreads();
        }
        if (tloc < tpb) counts[((size_t)(b * tpb + tloc)) * NPATCH + p] = carry + buf[tid] - v;
        carry += buf[511];
        __syncthreads();
    }
    unsigned start = carry < cap ? carry : cap;
    float* __restrict__ out_mask = out + (size_t)B * NPATCH * cap * 4;
    float4 z = make_float4(0.f, 0.f, 0.f, 0.f);
    for (unsigned idx = start + tid; idx < cap; idx += blockDim.x) {
        size_t o = (size_t)blockIdx.x * cap + idx;
        ((float4*)out)[o] = z;
        out_mask[o] = 0.0f;
    }
}

// K3: 4 waves per tile. Phase-1 tiles reuse saved per-wave hists (no count pass);
// suffix tiles of a saturated batch return instantly; otherwise local count pass.
__global__ void k_scatter(const float4* __restrict__ ev, const unsigned* __restrict__ offs,
                          const unsigned* __restrict__ whist_g,
                          const unsigned* __restrict__ totals1,
                          const int* __restrict__ p_cap, float* __restrict__ out,
                          int tile, int tpb, int T1pb, int B) {
    const int t = blockIdx.x;
    const int b = t / tpb, tloc = t - b * tpb;
    const int tid = threadIdx.x, lane = tid & 63, w = tid >> 6;
    const unsigned cap = (unsigned)p_cap[0];
    __shared__ int s_sat, s_any;
    __shared__ unsigned base_off[NPATCH];
    __shared__ unsigned cnt[4][NPATCH];
    __shared__ unsigned wh[4][NPATCH];
    if (tid == 0) { s_sat = 1; s_any = 0; }
    __syncthreads();
    if (tid < 16 && totals1[b * 16 + tid] < cap) s_sat = 0;  // benign race
    __syncthreads();
    const bool fast = (tloc < T1pb);
    if (!fast && s_sat) return;  // saturated suffix: nothing to write
    if (tid < 16) {
        unsigned v = offs[(size_t)t * NPATCH + tid];
        base_off[tid] = v;
        if (v < cap) s_any = 1;  // benign race
    }
    __syncthreads();
    if (!s_any) return;  // all groups past capacity at this tile

    const int chunk = tile >> 2, iters = chunk >> 6;
    const size_t cbase = (size_t)t * tile + (size_t)w * chunk;
    const unsigned long long lt = (1ull << lane) - 1ull;

    if (fast) {
        if (tid < 64) {
            int ww = tid >> 4, p = tid & 15;
            unsigned s = base_off[p];
            const unsigned* whp = whist_g + (size_t)(b * T1pb + tloc) * 64;
            for (int w2 = 0; w2 < ww; ++w2) s += whp[w2 * 16 + p];
            cnt[ww][p] = s;
        }
        __syncthreads();
    } else {
        if (tid < 64) wh[tid >> 4][tid & 15] = 0;
        __syncthreads();
        for (int it = 0; it < iters; ++it) {
            float4 e = ev[cbase + (size_t)it * 64 + lane];
            int p = patch_of(e.x, e.y);
            unsigned long long same = same_mask4(p);
            if ((same & lt) == 0ull) wh[w][p] += (unsigned)__popcll(same);
        }
        __syncthreads();
        if (tid < 64) {
            int ww = tid >> 4, p = tid & 15;
            unsigned s = base_off[p];
            for (int w2 = 0; w2 < ww; ++w2) s += wh[w2][p];
            cnt[ww][p] = s;
        }
        __syncthreads();
    }

    // Scatter: per-wave private counters; stable (tile -> wave chunk -> iter -> lane).
    float* __restrict__ out_mask = out + (size_t)B * NPATCH * cap * 4;
    for (int it = 0; it < iters; ++it) {
        float4 e = ev[cbase + (size_t)it * 64 + lane];
        int px = ((int)e.x) >> PATCH_SHIFT;
        px = px < 0 ? 0 : (px > GRID_W - 1 ? GRID_W - 1 : px);
        int py = ((int)e.y) >> PATCH_SHIFT;
        py = py < 0 ? 0 : (py > GRID_H - 1 ? GRID_H - 1 : py);
        int p = (py << 2) | px;

        unsigned long long same = same_mask4(p);
        unsigned before = (unsigned)__popcll(same & lt);
        unsigned cb = cnt[w][p];
        unsigned rank = cb + before;
        if (rank < cap) {
            size_t o = ((size_t)b * NPATCH + p) * cap + rank;
            float4 v;
            v.x = e.x - (float)(px << PATCH_SHIFT);
            v.y = e.y - (float)(py << PATCH_SHIFT);
            v.z = e.z;
            v.w = e.w;
            ((float4*)out)[o] = v;
            out_mask[o] = 1.0f;
        }
        if (before == 0) cnt[w][p] = cb + (unsigned)__popcll(same);
    }
}

extern "C" void kernel_launch(void* const* d_in, const int* in_sizes, int n_in,
                              void* d_out, int out_size, void* d_ws, size_t ws_size,
                              hipStream_t stream) {
    const float* events = (const float*)d_in[0];
    const int* p_cap = (const int*)d_in[1];

    const int C = 4;
    const long long N = (long long)in_sizes[0] / C;  // B*S
    const int B = (int)(N / S_LEN);

    int tile = 2048;
    for (;;) {
        long long T = N / tile;
        long long tpb = S_LEN / tile;
        long long T1pb = tpb >= 4 ? tpb / 4 : 1;
        size_t need = (size_t)(T * NPATCH + (long long)B * NPATCH + (long long)B * T1pb * 64) *
                      sizeof(unsigned);
        if (need <= ws_size || tile >= S_LEN) break;
        tile <<= 1;
    }
    const int T = (int)(N / tile);
    const int tpb = S_LEN / tile;
    const int T1pb = tpb >= 4 ? tpb / 4 : 1;

    unsigned* counts = (unsigned*)d_ws;
    unsigned* totals1 = counts + (size_t)T * NPATCH;
    unsigned* whist_g = totals1 + (size_t)B * NPATCH;

    k_hist1<<<B * T1pb, 256, 0, stream>>>((const float4*)events, counts, whist_g,
                                          tile, tpb, T1pb);
    k_scan1<<<B * NPATCH, 512, 0, stream>>>(counts, totals1, tpb, T1pb);
    if (tpb > T1pb)
        k_hist2<<<B * (tpb - T1pb), 256, 0, stream>>>((const float4*)events, counts,
                                                      totals1, p_cap, tile, tpb, T1pb);
    k_scan2<<<B * NPATCH, 512, 0, stream>>>(counts, totals1, p_cap, (float*)d_out,
                                            tpb, T1pb, B);
    k_scatter<<<T, 256, 0, stream>>>((const float4*)events, counts, whist_g, totals1,
                                     p_cap, (float*)d_out, tile, tpb, T1pb, B);
}

// Round 4
// 34.015 us; speedup vs baseline: 1.9676x; 1.1156x over previous
//
#include <hip/hip_runtime.h>
#include <cstddef>

// VectorizedPatchfier: capacity-limited stable counting sort into per-patch buffers.
// B=8, S=1<<20, C=4, grid 4x4 patches of 128x128 over a 512x512 canvas.
// Two-phase count: only the first 5/32 of each batch is histogrammed; if every
// group saturates (total >= cap) within that prefix -- true for uniform inputs
// at ~21 sigma -- the suffix is never read. k_meta's fallback path handles the
// general (non-saturating) case correctly, just slowly.

#define GRID_W 4
#define GRID_H 4
#define NPATCH 16
#define PATCH_SHIFT 7   // 128
#define S_LEN (1 << 20)
#define T1PB_MAX 128

__device__ __forceinline__ int patch_of(float fx, float fy) {
    int px = ((int)fx) >> PATCH_SHIFT;
    int py = ((int)fy) >> PATCH_SHIFT;
    px = px < 0 ? 0 : (px > GRID_W - 1 ? GRID_W - 1 : px);
    py = py < 0 ? 0 : (py > GRID_H - 1 ? GRID_H - 1 : py);
    return (py << 2) | px;
}

// Per-wave: mask of lanes whose 4-bit patch id matches this lane's.
__device__ __forceinline__ unsigned long long same_mask4(int p) {
    unsigned long long same = ~0ull;
#pragma unroll
    for (int b = 0; b < 4; ++b) {
        unsigned long long bal = __ballot((p >> b) & 1);
        same &= ((p >> b) & 1) ? bal : ~bal;
    }
    return same;
}

// K1: histogram of phase-1 tiles (first T1pb per batch); stores per-wave hists.
__global__ void k_hist1(const float4* __restrict__ ev, unsigned* __restrict__ counts,
                        unsigned* __restrict__ whist_g, int tile, int tpb, int T1pb) {
    const int blk = blockIdx.x;
    const int b = blk / T1pb, tloc = blk - b * T1pb;
    const int t = b * tpb + tloc;
    const int tid = threadIdx.x, lane = tid & 63, w = tid >> 6;
    __shared__ unsigned wh[4][NPATCH];
    if (tid < 64) wh[tid >> 4][tid & 15] = 0;
    __syncthreads();
    const int chunk = tile >> 2, iters = chunk >> 6;
    const size_t cbase = (size_t)t * tile + (size_t)w * chunk;
    const unsigned long long lt = (1ull << lane) - 1ull;
    for (int it = 0; it < iters; ++it) {
        float4 e = ev[cbase + (size_t)it * 64 + lane];
        int p = patch_of(e.x, e.y);
        unsigned long long same = same_mask4(p);
        if ((same & lt) == 0ull) wh[w][p] += (unsigned)__popcll(same);
    }
    __syncthreads();
    if (tid < 64) whist_g[(size_t)blk * 64 + tid] = wh[tid >> 4][tid & 15];
    if (tid < NPATCH)
        counts[(size_t)t * NPATCH + tid] =
            wh[0][tid] + wh[1][tid] + wh[2][tid] + wh[3][tid];
}

// K2: per-batch meta. Scan phase-1 counts in LDS, saturation check, satflag.
// Fallback (batch not saturated in phase 1): stream suffix tiles sequentially
// (count + scan), then zero unfilled tails. Never triggered for uniform input.
__global__ void k_meta(const float4* __restrict__ ev, unsigned* __restrict__ counts,
                       unsigned* __restrict__ satflag, const int* __restrict__ p_cap,
                       float* __restrict__ out, int tile, int tpb, int T1pb, int B) {
    const int b = blockIdx.x;
    const int tid = threadIdx.x, lane = tid & 63, w = tid >> 6;
    const unsigned cap = (unsigned)p_cap[0];
    __shared__ unsigned sc[T1PB_MAX][NPATCH];
    __shared__ unsigned s_tot[NPATCH];
    __shared__ int s_ok;

    for (int idx = tid; idx < T1pb * NPATCH; idx += blockDim.x) {
        int t = idx >> 4, p = idx & 15;
        sc[t][p] = counts[((size_t)(b * tpb + t)) * NPATCH + p];
    }
    if (tid == 0) s_ok = 1;
    __syncthreads();
    if (tid < NPATCH) {
        unsigned run = 0;
        for (int t = 0; t < T1pb; ++t) {
            unsigned v = sc[t][tid];
            sc[t][tid] = run;
            run += v;
        }
        s_tot[tid] = run;
        if (run < cap) s_ok = 0;  // benign race: all writers store 0
    }
    __syncthreads();
    for (int idx = tid; idx < T1pb * NPATCH; idx += blockDim.x) {
        int t = idx >> 4, p = idx & 15;
        counts[((size_t)(b * tpb + t)) * NPATCH + p] = sc[t][p];
    }
    if (tid == 0) satflag[b] = (unsigned)s_ok;
    if (s_ok) return;

    // ---- fallback: finish counting + scanning the suffix, zero tails ----
    __shared__ unsigned wh[4][NPATCH];
    __shared__ unsigned running[NPATCH];
    if (tid < NPATCH) running[tid] = s_tot[tid];
    const int chunk = tile >> 2, iters = chunk >> 6;
    const unsigned long long lt = (1ull << lane) - 1ull;
    for (int tloc = T1pb; tloc < tpb; ++tloc) {
        if (tid < 64) wh[tid >> 4][tid & 15] = 0;
        __syncthreads();
        const size_t cbase = ((size_t)(b * tpb + tloc)) * tile + (size_t)w * chunk;
        for (int it = 0; it < iters; ++it) {
            float4 e = ev[cbase + (size_t)it * 64 + lane];
            int p = patch_of(e.x, e.y);
            unsigned long long same = same_mask4(p);
            if ((same & lt) == 0ull) wh[w][p] += (unsigned)__popcll(same);
        }
        __syncthreads();
        if (tid < NPATCH) {
            counts[((size_t)(b * tpb + tloc)) * NPATCH + tid] = running[tid];
            running[tid] += wh[0][tid] + wh[1][tid] + wh[2][tid] + wh[3][tid];
        }
        __syncthreads();
    }
    float* __restrict__ out_mask = out + (size_t)B * NPATCH * cap * 4;
    float4 z = make_float4(0.f, 0.f, 0.f, 0.f);
    for (int p = 0; p < NPATCH; ++p) {
        unsigned total = running[p];
        unsigned start = total < cap ? total : cap;
        size_t gbase = ((size_t)b * NPATCH + p) * cap;
        for (unsigned idx = start + tid; idx < cap; idx += blockDim.x) {
            ((float4*)out)[gbase + idx] = z;
            out_mask[gbase + idx] = 0.0f;
        }
    }
}

// K3: 4 waves per tile. Phase-1 tiles reuse saved per-wave hists (no count pass);
// suffix tiles of a saturated batch return instantly; otherwise local count pass.
__global__ void k_scatter(const float4* __restrict__ ev, const unsigned* __restrict__ offs,
                          const unsigned* __restrict__ whist_g,
                          const unsigned* __restrict__ satflag,
                          const int* __restrict__ p_cap, float* __restrict__ out,
                          int tile, int tpb, int T1pb, int B) {
    const int t = blockIdx.x;
    const int b = t / tpb, tloc = t - b * tpb;
    const int tid = threadIdx.x, lane = tid & 63, w = tid >> 6;
    const unsigned cap = (unsigned)p_cap[0];
    __shared__ int s_sat, s_any;
    __shared__ unsigned base_off[NPATCH];
    __shared__ unsigned cnt[4][NPATCH];
    __shared__ unsigned wh[4][NPATCH];
    if (tid == 0) { s_sat = (int)satflag[b]; s_any = 0; }
    __syncthreads();
    const bool fast = (tloc < T1pb);
    if (!fast && s_sat) return;  // saturated suffix: nothing to write
    if (tid < 16) {
        unsigned v = offs[(size_t)t * NPATCH + tid];
        base_off[tid] = v;
        if (v < cap) s_any = 1;  // benign race
    }
    __syncthreads();
    if (!s_any) return;  // all groups past capacity at this tile

    const int chunk = tile >> 2, iters = chunk >> 6;
    const size_t cbase = (size_t)t * tile + (size_t)w * chunk;
    const unsigned long long lt = (1ull << lane) - 1ull;

    if (fast) {
        if (tid < 64) {
            int ww = tid >> 4, p = tid & 15;
            unsigned s = base_off[p];
            const unsigned* whp = whist_g + (size_t)(b * T1pb + tloc) * 64;
            for (int w2 = 0; w2 < ww; ++w2) s += whp[w2 * 16 + p];
            cnt[ww][p] = s;
        }
        __syncthreads();
    } else {
        if (tid < 64) wh[tid >> 4][tid & 15] = 0;
        __syncthreads();
        for (int it = 0; it < iters; ++it) {
            float4 e = ev[cbase + (size_t)it * 64 + lane];
            int p = patch_of(e.x, e.y);
            unsigned long long same = same_mask4(p);
            if ((same & lt) == 0ull) wh[w][p] += (unsigned)__popcll(same);
        }
        __syncthreads();
        if (tid < 64) {
            int ww = tid >> 4, p = tid & 15;
            unsigned s = base_off[p];
            for (int w2 = 0; w2 < ww; ++w2) s += wh[w2][p];
            cnt[ww][p] = s;
        }
        __syncthreads();
    }

    // Scatter: per-wave private counters; stable (tile -> wave chunk -> iter -> lane).
    float* __restrict__ out_mask = out + (size_t)B * NPATCH * cap * 4;
    for (int it = 0; it < iters; ++it) {
        float4 e = ev[cbase + (size_t)it * 64 + lane];
        int px = ((int)e.x) >> PATCH_SHIFT;
        px = px < 0 ? 0 : (px > GRID_W - 1 ? GRID_W - 1 : px);
        int py = ((int)e.y) >> PATCH_SHIFT;
        py = py < 0 ? 0 : (py > GRID_H - 1 ? GRID_H - 1 : py);
        int p = (py << 2) | px;

        unsigned long long same = same_mask4(p);
        unsigned before = (unsigned)__popcll(same & lt);
        unsigned cb = cnt[w][p];
        unsigned rank = cb + before;
        if (rank < cap) {
            size_t o = ((size_t)b * NPATCH + p) * cap + rank;
            float4 v;
            v.x = e.x - (float)(px << PATCH_SHIFT);
            v.y = e.y - (float)(py << PATCH_SHIFT);
            v.z = e.z;
            v.w = e.w;
            ((float4*)out)[o] = v;
            out_mask[o] = 1.0f;
        }
        if (before == 0) cnt[w][p] = cb + (unsigned)__popcll(same);
    }
}

extern "C" void kernel_launch(void* const* d_in, const int* in_sizes, int n_in,
                              void* d_out, int out_size, void* d_ws, size_t ws_size,
                              hipStream_t stream) {
    const float* events = (const float*)d_in[0];
    const int* p_cap = (const int*)d_in[1];

    const int C = 4;
    const long long N = (long long)in_sizes[0] / C;  // B*S
    const int B = (int)(N / S_LEN);

    int tile = 2048, tpb, T1pb;
    for (;;) {
        long long T = N / tile;
        tpb = (int)(S_LEN / tile);
        T1pb = tpb;
        if (tpb >= 32) T1pb = (tpb * 5) / 32;   // 5/32 of the batch; 80 tiles at tile=2048
        if (T1pb > T1PB_MAX) T1pb = T1PB_MAX;
        size_t need = ((size_t)T * NPATCH + (size_t)B * T1pb * 64 + B) * sizeof(unsigned);
        if (need <= ws_size || tile >= S_LEN) break;
        tile <<= 1;
    }
    const int T = (int)(N / tile);

    unsigned* counts = (unsigned*)d_ws;
    unsigned* whist_g = counts + (size_t)T * NPATCH;
    unsigned* satflag = whist_g + (size_t)B * T1pb * 64;

    k_hist1<<<B * T1pb, 256, 0, stream>>>((const float4*)events, counts, whist_g,
                                          tile, tpb, T1pb);
    k_meta<<<B, 256, 0, stream>>>((const float4*)events, counts, satflag, p_cap,
                                  (float*)d_out, tile, tpb, T1pb, B);
    k_scatter<<<T, 256, 0, stream>>>((const float4*)events, counts, whist_g, satflag,
                                     p_cap, (float*)d_out, tile, tpb, T1pb, B);
}